// Round 3
// baseline (18091.646 us; speedup 1.0000x reference)
//
#include <hip/hip_runtime.h>

// Problem constants (match reference setup_inputs)
#define N_VOX   120000
#define NUP_VOX 240000
constexpr float BN_EPS = 1e-5f;

__device__ __forceinline__ float lrelu(float x) { return x >= 0.f ? x : 0.01f * x; }

// ---------------------------------------------------------------------------
// Tiled gather-GEMM-scatter sparse conv.
// Per block: k = blockIdx.y fixed; W[k] (CIN x 64) staged once into LDS.
// Per tile: TE map entries gathered into LDS as A^T (CIN x TE, padded),
// using per-lane float4 loads (high MLP). Then a register-tiled GEMM:
// 256 threads as 16(tm) x 16(tn); each thread computes TM entries x 4 co
// with FMAs fed by LDS vector reads. Scatter via atomicAdd.
// ---------------------------------------------------------------------------
template <int CIN, int TE>
__global__ __launch_bounds__(256) void sconv_gemm_kernel(
    const float* __restrict__ feats, const float* __restrict__ W,
    const int* __restrict__ idx_in, const int* __restrict__ idx_out,
    float* __restrict__ out, int M)
{
    constexpr int PAD = TE + 4;        // padded A^T row stride (floats), 16B-aligned
    constexpr int TM  = TE / 16;       // entries per thread
    constexpr int TPE = 256 / TE;      // threads per entry (staging)
    constexpr int CPT = CIN / TPE;     // floats per thread (staging) == 16

    __shared__ float At[CIN][PAD];
    __shared__ float Wl[CIN][64];
    __shared__ int   okl[TE];

    const int t  = threadIdx.x;
    const int k  = blockIdx.y;
    const int tn = t & 15;             // co group (4 channels)
    const int tm = t >> 4;             // entry group (TM entries)
    const int e  = t / TPE;            // staging entry
    const int sc = t % TPE;            // staging quarter within the row

    // Stage W[k] into LDS (contiguous copy; covered by the in-loop barrier).
    const float4* Wk4 = (const float4*)(W + (size_t)k * CIN * 64);
    for (int i = t; i < CIN * 16; i += 256)
        ((float4*)&Wl[0][0])[i] = Wk4[i];

    const int* ikp = idx_in  + (size_t)k * M;
    const int* okp = idx_out + (size_t)k * M;

    for (int tile = blockIdx.x; tile * TE < M; tile += gridDim.x) {
        const int m0 = tile * TE;
        __syncthreads();               // protect LDS from previous iteration
        if (t < TE) okl[t] = okp[m0 + t];
        const int ik = ikp[m0 + e];
        const float4* row4 = (const float4*)(feats + (size_t)ik * CIN + sc * CPT);
        float4 v[CPT / 4];
#pragma unroll
        for (int j = 0; j < CPT / 4; ++j) v[j] = row4[j];
#pragma unroll
        for (int j = 0; j < CPT / 4; ++j) {
            const int ci = sc * CPT + j * 4;
            At[ci + 0][e] = v[j].x;
            At[ci + 1][e] = v[j].y;
            At[ci + 2][e] = v[j].z;
            At[ci + 3][e] = v[j].w;
        }
        __syncthreads();

        float acc[TM][4];
#pragma unroll
        for (int i = 0; i < TM; ++i)
#pragma unroll
            for (int j = 0; j < 4; ++j) acc[i][j] = 0.f;

#pragma unroll 4
        for (int ci = 0; ci < CIN; ++ci) {
            float a[TM];
            if constexpr (TM == 4) {
                float4 av = *(const float4*)&At[ci][tm * 4];
                a[0] = av.x; a[1] = av.y; a[2] = av.z; a[3] = av.w;
            } else {
                float2 av = *(const float2*)&At[ci][tm * 2];
                a[0] = av.x; a[1] = av.y;
            }
            float4 b = *(const float4*)&Wl[ci][tn * 4];
#pragma unroll
            for (int i = 0; i < TM; ++i) {
                acc[i][0] = fmaf(a[i], b.x, acc[i][0]);
                acc[i][1] = fmaf(a[i], b.y, acc[i][1]);
                acc[i][2] = fmaf(a[i], b.z, acc[i][2]);
                acc[i][3] = fmaf(a[i], b.w, acc[i][3]);
            }
        }

#pragma unroll
        for (int i = 0; i < TM; ++i) {
            const int o = okl[tm * TM + i];
            float* po = out + (size_t)o * 64 + tn * 4;
            atomicAdd(po + 0, acc[i][0]);
            atomicAdd(po + 1, acc[i][1]);
            atomicAdd(po + 2, acc[i][2]);
            atomicAdd(po + 3, acc[i][3]);
        }
    }
}

// ---------------------------------------------------------------------------
// Per-channel sum & sumsq of lrelu(x) over R rows (64 channels).
// ---------------------------------------------------------------------------
__global__ __launch_bounds__(256) void stats_kernel(
    const float* __restrict__ x, int R, float* __restrict__ st)
{
    const int lane = threadIdx.x & 63;
    const int wv   = threadIdx.x >> 6;
    float s = 0.f, q = 0.f;
    const int stride = gridDim.x * 4;
    for (int r = blockIdx.x * 4 + wv; r < R; r += stride) {
        float v = lrelu(x[(size_t)r * 64 + lane]);
        s += v;
        q = fmaf(v, v, q);
    }
    __shared__ float ls[4][64];
    __shared__ float lq[4][64];
    ls[wv][lane] = s;
    lq[wv][lane] = q;
    __syncthreads();
    if (wv == 0) {
        float S = ls[0][lane] + ls[1][lane] + ls[2][lane] + ls[3][lane];
        float Q = lq[0][lane] + lq[1][lane] + lq[2][lane] + lq[3][lane];
        atomicAdd(&st[lane], S);
        atomicAdd(&st[64 + lane], Q);
    }
}

// ---------------------------------------------------------------------------
// y = (lrelu(x) - mean) * rsqrt(var + eps) * g + b   (channel-wise), float4.
// ---------------------------------------------------------------------------
__global__ __launch_bounds__(256) void bn_apply_kernel(
    const float* __restrict__ x, float* __restrict__ y,
    const float* __restrict__ st, const float* __restrict__ g,
    const float* __restrict__ b, int R)
{
    __shared__ float sc[64];
    __shared__ float sh[64];
    const float invR = 1.f / (float)R;
    if (threadIdx.x < 64) {
        int ch = threadIdx.x;
        float m = st[ch] * invR;
        float v = st[64 + ch] * invR - m * m;
        float s = rsqrtf(v + BN_EPS) * g[ch];
        sc[ch] = s;
        sh[ch] = fmaf(-m, s, b[ch]);
    }
    __syncthreads();

    const size_t total = (size_t)R * 16;  // float4 count (64 ch / 4)
    size_t i = (size_t)blockIdx.x * blockDim.x + threadIdx.x;
    const size_t stride = (size_t)gridDim.x * blockDim.x;
    const float4* xv = (const float4*)x;
    float4* yv = (float4*)y;
    for (; i < total; i += stride) {
        int ch = (int)((i * 4) & 63);
        float4 v = xv[i];
        float4 o;
        o.x = fmaf(lrelu(v.x), sc[ch + 0], sh[ch + 0]);
        o.y = fmaf(lrelu(v.y), sc[ch + 1], sh[ch + 1]);
        o.z = fmaf(lrelu(v.z), sc[ch + 2], sh[ch + 2]);
        o.w = fmaf(lrelu(v.w), sc[ch + 3], sh[ch + 3]);
        yv[i] = o;
    }
}

extern "C" void kernel_launch(void* const* d_in, const int* in_sizes, int n_in,
                              void* d_out, int out_size, void* d_ws, size_t ws_size,
                              hipStream_t stream)
{
    const float* x_F   = (const float*)d_in[0];
    const float* skipF = (const float*)d_in[1];
    const float* Wt    = (const float*)d_in[2];
    const float* Wu    = (const float*)d_in[3];
    const float* W1    = (const float*)d_in[4];
    const float* W2    = (const float*)d_in[5];
    const float* W3    = (const float*)d_in[6];
    const float* g0 = (const float*)d_in[7];
    const float* b0 = (const float*)d_in[8];
    const float* g1 = (const float*)d_in[9];
    const float* b1 = (const float*)d_in[10];
    const float* g2 = (const float*)d_in[11];
    const float* b2 = (const float*)d_in[12];
    const float* g3 = (const float*)d_in[13];
    const float* b3 = (const float*)d_in[14];
    const int* mt_in  = (const int*)d_in[15];
    const int* mt_out = (const int*)d_in[16];
    const int* mu_in  = (const int*)d_in[17];
    const int* mu_out = (const int*)d_in[18];
    const int* m1_in  = (const int*)d_in[19];
    const int* m1_out = (const int*)d_in[20];
    const int* m2_in  = (const int*)d_in[21];
    const int* m2_out = (const int*)d_in[22];
    const int* m3_in  = (const int*)d_in[23];
    const int* m3_out = (const int*)d_in[24];

    // Workspace layout (f32): s0 [N,64], s1 [NUP,64], st [128].
    // d_out doubles as the second NUP x 64 scratch buffer (s2).
    float* s0 = (float*)d_ws;
    float* s1 = s0 + (size_t)N_VOX * 64;
    float* st = s1 + (size_t)NUP_VOX * 64;
    float* s2 = (float*)d_out;

    const dim3 blk(256);

    // ---- Stage 0: trans_dilao conv (Cin=128) -> lrelu -> BN, in s0 ----
    hipMemsetAsync(s0, 0, (size_t)N_VOX * 64 * sizeof(float), stream);
    hipMemsetAsync(st, 0, 128 * sizeof(float), stream);
    sconv_gemm_kernel<128, 32><<<dim3(64, 27), blk, 0, stream>>>(x_F, Wt, mt_in, mt_out, s0, N_VOX);
    stats_kernel<<<dim3(768), blk, 0, stream>>>(s0, N_VOX, st);
    bn_apply_kernel<<<dim3(1024), blk, 0, stream>>>(s0, s0, st, g0, b0, N_VOX);

    // ---- Stage 1: transposed upsample conv + skip, in s1 ----
    hipMemcpyAsync(s1, skipF, (size_t)NUP_VOX * 64 * sizeof(float),
                   hipMemcpyDeviceToDevice, stream);
    sconv_gemm_kernel<64, 64><<<dim3(64, 27), blk, 0, stream>>>(s0, Wu, mu_in, mu_out, s1, NUP_VOX);

    // ---- Stage 2: conv1 (K=9) -> lrelu -> BN, in d_out ----
    hipMemsetAsync(s2, 0, (size_t)NUP_VOX * 64 * sizeof(float), stream);
    hipMemsetAsync(st, 0, 128 * sizeof(float), stream);
    sconv_gemm_kernel<64, 64><<<dim3(192, 9), blk, 0, stream>>>(s1, W1, m1_in, m1_out, s2, NUP_VOX);
    stats_kernel<<<dim3(768), blk, 0, stream>>>(s2, NUP_VOX, st);
    bn_apply_kernel<<<dim3(2048), blk, 0, stream>>>(s2, s2, st, g1, b1, NUP_VOX);

    // ---- Stage 3: conv2 (K=9) -> lrelu -> BN, in s1 ----
    hipMemsetAsync(s1, 0, (size_t)NUP_VOX * 64 * sizeof(float), stream);
    hipMemsetAsync(st, 0, 128 * sizeof(float), stream);
    sconv_gemm_kernel<64, 64><<<dim3(192, 9), blk, 0, stream>>>(s2, W2, m2_in, m2_out, s1, NUP_VOX);
    stats_kernel<<<dim3(768), blk, 0, stream>>>(s1, NUP_VOX, st);
    bn_apply_kernel<<<dim3(2048), blk, 0, stream>>>(s1, s1, st, g2, b2, NUP_VOX);

    // ---- Stage 4: conv3 (K=27) -> lrelu -> BN -> d_out ----
    hipMemsetAsync(s2, 0, (size_t)NUP_VOX * 64 * sizeof(float), stream);
    hipMemsetAsync(st, 0, 128 * sizeof(float), stream);
    sconv_gemm_kernel<64, 64><<<dim3(64, 27), blk, 0, stream>>>(s1, W3, m3_in, m3_out, s2, NUP_VOX);
    stats_kernel<<<dim3(768), blk, 0, stream>>>(s2, NUP_VOX, st);
    bn_apply_kernel<<<dim3(2048), blk, 0, stream>>>(s2, s2, st, g3, b3, NUP_VOX);
}